// Round 15
// baseline (1119.779 us; speedup 1.0000x reference)
//
#include <hip/hip_runtime.h>
#include <hip/hip_cooperative_groups.h>
#include <stdint.h>

namespace cg = cooperative_groups;

#define N_NODES 32768
#define N_EDGES 262144
#define NB 8
#define TW 25

typedef __attribute__((ext_vector_type(8))) short short8;
typedef __attribute__((ext_vector_type(4))) float floatx4;

#if defined(__has_builtin)
#if __has_builtin(__builtin_amdgcn_cvt_pk_bf16_f32)
#define HAVE_CVT_PK_BF16 1
#endif
#endif

// swish via HW approximate reciprocal (v_rcp_f32): ~1-ulp rel error,
// far below bf16 quantization; avoids the ~10-instr IEEE divide sequence.
__device__ __forceinline__ float swishf(float x) {
    return x * __builtin_amdgcn_rcpf(1.0f + __expf(-x));
}

__device__ __forceinline__ unsigned short f2bf(float x) {
    union { float f; unsigned u; } v; v.f = x;
    unsigned r = v.u + 0x7FFFu + ((v.u >> 16) & 1u);
    return (unsigned short)(r >> 16);
}
// packed f32x2 -> bf16x2 (low = a, high = b); HW v_cvt_pk_bf16_f32 on gfx950
__device__ __forceinline__ unsigned pkbf(float a, float b) {
#ifdef HAVE_CVT_PK_BF16
    typedef __attribute__((ext_vector_type(2))) __bf16 bf16x2;
    union { bf16x2 v; unsigned u; } cv;
    cv.v = __builtin_amdgcn_cvt_pk_bf16_f32(a, b);
    return cv.u;
#else
    return (unsigned)f2bf(a) | ((unsigned)f2bf(b) << 16);
#endif
}
__device__ __forceinline__ float bf2f(unsigned short b) {
    union { unsigned u; float f; } v; v.u = ((unsigned)b) << 16; return v.f;
}

// ---------------------------------------------------------------------------
__global__ void init_kernel(const float* __restrict__ pos,
                            float* __restrict__ posx, float* __restrict__ post) {
    int i = blockIdx.x * 256 + threadIdx.x;
    if (i < N_NODES) {
        post[i] = pos[i * 2 + 0] * 0.25f;
        posx[i] = pos[i * 2 + 1] * 0.0625f;
    }
}

__global__ void deg_kernel(const int* __restrict__ tgt, int* __restrict__ deg) {
    int i = blockIdx.x * 256 + threadIdx.x;
    if (i < N_EDGES) atomicAdd(&deg[tgt[i]], 1);
}

// exclusive scan of deg -> cursor, single block
__global__ __launch_bounds__(1024) void scan_kernel(const int* __restrict__ deg,
                                                    int* __restrict__ cursor) {
    __shared__ int ps[1024];
    int t = threadIdx.x;
    int base = t * 32;
    int tot = 0;
    for (int i = 0; i < 32; ++i) tot += deg[base + i];
    ps[t] = tot;
    __syncthreads();
    for (int off = 1; off < 1024; off <<= 1) {
        int v = (t >= off) ? ps[t - off] : 0;
        __syncthreads();
        ps[t] += v;
        __syncthreads();
    }
    int run = ps[t] - tot;
    for (int i = 0; i < 32; ++i) {
        cursor[base + i] = run;
        run += deg[base + i];
    }
}

// tgt-sorted edge arrays directly
__global__ void scatter_kernel(const int* __restrict__ src, const int* __restrict__ tgt,
                               int* __restrict__ cursor,
                               int* __restrict__ src_s, int* __restrict__ tgt_s) {
    int i = blockIdx.x * 256 + threadIdx.x;
    if (i < N_EDGES) {
        int tg = tgt[i];
        int p = atomicAdd(&cursor[tg], 1);
        src_s[p] = src[i];
        tgt_s[p] = tg;
    }
}

// layer-invariant edge features, tgt-sorted order: [u_diff(25), pxd, post_t, 0x5]
__global__ __launch_bounds__(256) void ediff_kernel(
    const float* __restrict__ u, const float* __restrict__ posx,
    const float* __restrict__ post,
    const int* __restrict__ src_s, const int* __restrict__ tgt_s,
    unsigned short* __restrict__ ediff)
{
    int e = blockIdx.x * 256 + threadIdx.x;
    if (e >= N_EDGES) return;
    int s = src_s[e], g = tgt_s[e];
    float fv[32];
    #pragma unroll
    for (int k = 0; k < 32; ++k) fv[k] = 0.f;
    #pragma unroll
    for (int k = 0; k < 25; ++k)
        fv[k] = u[(size_t)g * 25 + k] - u[(size_t)s * 25 + k];
    fv[25] = posx[g] - posx[s];
    fv[26] = post[g];
    unsigned pk[16];
    #pragma unroll
    for (int j = 0; j < 16; ++j) pk[j] = pkbf(fv[2 * j], fv[2 * j + 1]);
    #pragma unroll
    for (int j = 0; j < 4; ++j)
        *(uint4*)(ediff + (size_t)e * 32 + j * 8) = *(uint4*)&pk[j * 4];
}

// ---------------------------------------------------------------------------
// Pack weight into MFMA B-frag order: frag id = ((l*Kc + c)*8 + t8)*64 + lane,
// lane holds B[k=c*32+(lane>>4)*8+j][n=t8*16+(lane&15)], j=0..7.
__global__ __launch_bounds__(256) void pack_kernel(const float* __restrict__ W,
                                                   unsigned short* __restrict__ Wp,
                                                   int Kreal, int Kc, int total) {
    int id = blockIdx.x * 256 + threadIdx.x;
    if (id >= total) return;
    int lane = id & 63;
    int t8 = (id >> 6) & 7;
    int rest = id >> 9;
    int c = rest % Kc;
    int l = rest / Kc;
    int n = t8 * 16 + (lane & 15);
    int kb = c * 32 + (lane >> 4) * 8;
    short8 v;
    #pragma unroll
    for (int j = 0; j < 8; ++j) {
        int k = kb + j;
        float x = (k < Kreal) ? W[((size_t)l * Kreal + k) * 128 + n] : 0.f;
        v[j] = (short)f2bf(x);
    }
    *(short8*)(Wp + (size_t)id * 8) = v;
}

// ---------------------------------------------------------------------------
// Encoder; writes h_bf only; zeroes this block's agg slice
__global__ __launch_bounds__(256) void encoder_kernel(
    const float* __restrict__ u, const float* __restrict__ posx,
    const float* __restrict__ post,
    const float* __restrict__ We1, const float* __restrict__ be1,
    const float* __restrict__ We2, const float* __restrict__ be2,
    unsigned short* __restrict__ h_bf, float* __restrict__ agg)
{
    __shared__ __align__(16) float As[64 * 36];
    __shared__ __align__(16) float Ws[32 * 128];
    __shared__ __align__(16) float Ms[64 * 128];

    int t = threadIdx.x;
    int n0 = blockIdx.x * 64;
    int rg = t >> 5, cg = t & 31;

    {   // zero agg slice
        int r = t & 63, cseg = t >> 6;
        float4 z = make_float4(0.f, 0.f, 0.f, 0.f);
        #pragma unroll
        for (int j = 0; j < 8; ++j)
            *(float4*)(agg + (size_t)(n0 + r) * 128 + cseg * 32 + j * 4) = z;
    }

    float acc[8][4] = {};
    {
        int kk = t >> 3, cb = (t & 7) * 16;
        #pragma unroll
        for (int j = 0; j < 4; ++j) {
            float4 w = make_float4(0.f, 0.f, 0.f, 0.f);
            if (kk < 27) w = *(const float4*)&We1[kk * 128 + cb + j * 4];
            *(float4*)&Ws[kk * 128 + cb + j * 4] = w;
        }
        int el = t >> 2, kb = (t & 3) * 8, n = n0 + el;
        float v[8];
        #pragma unroll
        for (int j = 0; j < 8; ++j) {
            int k = kb + j;
            float x = 0.f;
            if (k < 25) x = u[n * 25 + k];
            else if (k == 25) x = posx[n];
            else if (k == 26) x = post[n];
            v[j] = x;
        }
        #pragma unroll
        for (int j = 0; j < 8; j += 4)
            *(float4*)&As[el * 36 + kb + j] = make_float4(v[j], v[j+1], v[j+2], v[j+3]);
        __syncthreads();
        #pragma unroll 4
        for (int kk2 = 0; kk2 < 32; ++kk2) {
            float4 b = *(const float4*)&Ws[kk2 * 128 + cg * 4];
            float a[8];
            #pragma unroll
            for (int i = 0; i < 8; ++i) a[i] = As[(rg * 8 + i) * 36 + kk2];
            #pragma unroll
            for (int i = 0; i < 8; ++i) {
                acc[i][0] += a[i] * b.x; acc[i][1] += a[i] * b.y;
                acc[i][2] += a[i] * b.z; acc[i][3] += a[i] * b.w;
            }
        }
        __syncthreads();
    }
    {
        float4 b1 = *(const float4*)&be1[cg * 4];
        #pragma unroll
        for (int i = 0; i < 8; ++i) {
            float4 m;
            m.x = swishf(acc[i][0] + b1.x);
            m.y = swishf(acc[i][1] + b1.y);
            m.z = swishf(acc[i][2] + b1.z);
            m.w = swishf(acc[i][3] + b1.w);
            *(float4*)&Ms[(rg * 8 + i) * 128 + cg * 4] = m;
        }
        __syncthreads();
    }
    float acc2[8][4] = {};
    for (int k0 = 0; k0 < 128; k0 += 32) {
        int kk = t >> 3, cb = (t & 7) * 16;
        #pragma unroll
        for (int j = 0; j < 4; ++j)
            *(float4*)&Ws[kk * 128 + cb + j * 4] =
                *(const float4*)&We2[(k0 + kk) * 128 + cb + j * 4];
        __syncthreads();
        #pragma unroll 4
        for (int kk2 = 0; kk2 < 32; ++kk2) {
            float4 b = *(const float4*)&Ws[kk2 * 128 + cg * 4];
            float a[8];
            #pragma unroll
            for (int i = 0; i < 8; ++i) a[i] = Ms[(rg * 8 + i) * 128 + (k0 + kk2)];
            #pragma unroll
            for (int i = 0; i < 8; ++i) {
                acc2[i][0] += a[i] * b.x; acc2[i][1] += a[i] * b.y;
                acc2[i][2] += a[i] * b.z; acc2[i][3] += a[i] * b.w;
            }
        }
        __syncthreads();
    }
    {
        float4 b2 = *(const float4*)&be2[cg * 4];
        #pragma unroll
        for (int i = 0; i < 8; ++i) {
            int n = n0 + rg * 8 + i;
            float4 o;
            o.x = swishf(acc2[i][0] + b2.x);
            o.y = swishf(acc2[i][1] + b2.y);
            o.z = swishf(acc2[i][2] + b2.z);
            o.w = swishf(acc2[i][3] + b2.w);
            uint2 pk;
            pk.x = pkbf(o.x, o.y);
            pk.y = pkbf(o.z, o.w);
            *(uint2*)(h_bf + (size_t)n * 128 + cg * 4) = pk;
        }
    }
}

// ---------------------------------------------------------------------------
// Message MLP: 64 tgt-sorted edges/block, 512 threads (8 waves), wave owns
// N-tile w over 4 M-groups. Static LDS 38 KB -> 4 blocks/CU (32 waves/CU).
__global__ __launch_bounds__(512, 8) void message_kernel(
    const unsigned short* __restrict__ h_bf,
    const unsigned short* __restrict__ ediff,
    const int* __restrict__ src_s, const int* __restrict__ tgt_s,
    const unsigned short* __restrict__ W1p, const float* __restrict__ b1,
    const unsigned short* __restrict__ W2p, const float* __restrict__ b2,
    float* __restrict__ agg, float* __restrict__ stats)
{
    __shared__ __align__(16) unsigned short SH[64 * 296];  // 37888 B
    __shared__ int tgtS[64];
    unsigned short* Msh = SH;          // 64 x 136
    unsigned short* Cs  = SH + 9216;   // byte 18432: 64 x 132

    int t = threadIdx.x;
    int e0 = blockIdx.x * 64;
    if (blockIdx.x == 0 && t < 256) {  // zero stats for this layer
        float4 z = make_float4(0.f, 0.f, 0.f, 0.f);
        *(float4*)&stats[t * 8] = z;
        *(float4*)&stats[t * 8 + 4] = z;
    }
    if (t < 64) tgtS[t] = tgt_s[e0 + t];

    // ---- stage A into LDS: 8 threads per row (r = t&63, cseg = t>>6)
    {
        int r = t & 63, cseg = t >> 6;
        int g = tgt_s[e0 + r], s = src_s[e0 + r];
        const short8* hg = (const short8*)(h_bf + (size_t)g * 128);
        const short8* hs = (const short8*)(h_bf + (size_t)s * 128);
        #pragma unroll
        for (int j = 0; j < 2; ++j) {
            int chunk = cseg * 2 + j;  // 0..15
            *(short8*)(SH + r * 296 + chunk * 8)       = hg[chunk];
            *(short8*)(SH + r * 296 + 128 + chunk * 8) = hs[chunk];
        }
        if (cseg < 4)
            *(short8*)(SH + r * 296 + 256 + cseg * 8) =
                *(const short8*)(ediff + (size_t)(e0 + r) * 32 + cseg * 8);
    }
    __syncthreads();

    int w = t >> 6, lane = t & 63, q = lane >> 4, m = lane & 15;

    // ---- GEMM1: K=288 (9 chunks), tile w, 4 M-groups
    floatx4 acc[4] = {};
    #pragma unroll
    for (int c = 0; c < 9; ++c) {
        short8 b = *(const short8*)(W1p + ((size_t)(c * 8 + w) * 64 + lane) * 8);
        #pragma unroll
        for (int g2 = 0; g2 < 4; ++g2) {
            short8 a = *(const short8*)(SH + (g2 * 16 + m) * 296 + c * 32 + q * 8);
            acc[g2] = __builtin_amdgcn_mfma_f32_16x16x32_bf16(a, b, acc[g2], 0, 0, 0);
        }
    }
    __syncthreads();  // A region dead

    // ---- epilogue 1 -> Ms (packed bf16 conversion, write b16 lo/hi)
    {
        int col = w * 16 + m;
        float bv = b1[col];
        #pragma unroll
        for (int g2 = 0; g2 < 4; ++g2) {
            unsigned p01 = pkbf(swishf(acc[g2][0] + bv), swishf(acc[g2][1] + bv));
            unsigned p23 = pkbf(swishf(acc[g2][2] + bv), swishf(acc[g2][3] + bv));
            int base = g2 * 16 + q * 4;
            Msh[(base + 0) * 136 + col] = (unsigned short)p01;
            Msh[(base + 1) * 136 + col] = (unsigned short)(p01 >> 16);
            Msh[(base + 2) * 136 + col] = (unsigned short)p23;
            Msh[(base + 3) * 136 + col] = (unsigned short)(p23 >> 16);
        }
    }
    __syncthreads();

    // ---- GEMM2: K=128 (4 chunks)
    floatx4 acc2[4] = {};
    #pragma unroll
    for (int c = 0; c < 4; ++c) {
        short8 b = *(const short8*)(W2p + ((size_t)(c * 8 + w) * 64 + lane) * 8);
        #pragma unroll
        for (int g2 = 0; g2 < 4; ++g2) {
            short8 a = *(const short8*)(Msh + (g2 * 16 + m) * 136 + c * 32 + q * 8);
            acc2[g2] = __builtin_amdgcn_mfma_f32_16x16x32_bf16(a, b, acc2[g2], 0, 0, 0);
        }
    }
    // ---- epilogue 2 -> Cs (disjoint from Ms)
    {
        int col = w * 16 + m;
        float bv = b2[col];
        #pragma unroll
        for (int g2 = 0; g2 < 4; ++g2) {
            unsigned p01 = pkbf(swishf(acc2[g2][0] + bv), swishf(acc2[g2][1] + bv));
            unsigned p23 = pkbf(swishf(acc2[g2][2] + bv), swishf(acc2[g2][3] + bv));
            int base = g2 * 16 + q * 4;
            Cs[(base + 0) * 132 + col] = (unsigned short)p01;
            Cs[(base + 1) * 132 + col] = (unsigned short)(p01 >> 16);
            Cs[(base + 2) * 132 + col] = (unsigned short)p23;
            Cs[(base + 3) * 132 + col] = (unsigned short)(p23 >> 16);
        }
    }
    __syncthreads();

    // ---- reduction: all 512 threads; col = t&127, segment = (t>>7)*16 rows
    {
        int col = t & 127, seg = t >> 7;
        int r0 = seg * 16;
        float run = 0.f;
        int prev = tgtS[r0];
        bool atStart = true;
        #pragma unroll 4
        for (int i = 0; i < 16; ++i) {
            int tg = tgtS[r0 + i];
            if (tg != prev) {
                float* dst = &agg[(size_t)prev * 128 + col];
                if (atStart) atomicAdd(dst, run);
                else *dst = run;
                run = 0.f; prev = tg; atStart = false;
            }
            run += bf2f(Cs[(r0 + i) * 132 + col]);
        }
        atomicAdd(&agg[(size_t)prev * 128 + col], run);
    }
}

// ---------------------------------------------------------------------------
// Fused Update+Norm (cooperative, round-15): 64 nodes/block, 512 threads,
// grid 512 = exactly 2 blocks/CU. Phase 1: update MLP, hv kept in registers,
// stats accumulated via device-scope atomicAdd. grid.sync(). Phase 2: read
// stats via device-scope atomic RMW (+0.0f) — executes at the coherence
// point, immune to per-XCD L2 staleness (the R11 bug) — then normalize
// in-register and write h_bf once. No hraw buffer, no norm kernel.
__global__ __launch_bounds__(512, 4) void update_norm_kernel(
    unsigned short* __restrict__ h_bf,
    float* __restrict__ agg, const int* __restrict__ deg,
    const float* __restrict__ post,
    const unsigned short* __restrict__ W1p, const float* __restrict__ b1,
    const unsigned short* __restrict__ W2p, const float* __restrict__ b2,
    float* __restrict__ stats)
{
    __shared__ __align__(16) unsigned short SH[64 * 296 + 64 * 136];  // 55296 B
    __shared__ float statsS[256];
    unsigned short* Msh = SH + 64 * 296;

    int t = threadIdx.x;
    int n0 = blockIdx.x * 64;

    // ---- stage A = [h_bf | agg/deg (bf16) | post-pad]: 8 threads/row
    {
        int r = t & 63, cseg = t >> 6;
        int n = n0 + r;
        const short8* hn = (const short8*)(h_bf + (size_t)n * 128);
        #pragma unroll
        for (int j = 0; j < 2; ++j) {
            int chunk = cseg * 2 + j;
            *(short8*)(SH + r * 296 + chunk * 8) = hn[chunk];
        }
        float ic = __builtin_amdgcn_rcpf(fmaxf((float)deg[n], 1.0f));
        #pragma unroll
        for (int j = 0; j < 2; ++j) {
            int unit = cseg * 2 + j;
            const float* ap = agg + (size_t)n * 128 + unit * 8;
            float4 v0 = *(const float4*)ap;
            float4 v1 = *(const float4*)(ap + 4);
            unsigned pa[4];
            pa[0] = pkbf(v0.x * ic, v0.y * ic);
            pa[1] = pkbf(v0.z * ic, v0.w * ic);
            pa[2] = pkbf(v1.x * ic, v1.y * ic);
            pa[3] = pkbf(v1.z * ic, v1.w * ic);
            *(uint4*)(SH + r * 296 + 128 + unit * 8) = *(uint4*)pa;
        }
        if (cseg < 4) {
            short8 z;
            #pragma unroll
            for (int k = 0; k < 8; ++k) z[k] = 0;
            if (cseg == 0) z[0] = (short)f2bf(post[n]);  // k=256
            *(short8*)(SH + r * 296 + 256 + cseg * 8) = z;
        }
    }
    __syncthreads();

    int w = t >> 6, lane = t & 63, q = lane >> 4, m = lane & 15;

    floatx4 acc[4] = {};
    #pragma unroll
    for (int c = 0; c < 9; ++c) {
        short8 b = *(const short8*)(W1p + ((size_t)(c * 8 + w) * 64 + lane) * 8);
        #pragma unroll
        for (int g2 = 0; g2 < 4; ++g2) {
            short8 a = *(const short8*)(SH + (g2 * 16 + m) * 296 + c * 32 + q * 8);
            acc[g2] = __builtin_amdgcn_mfma_f32_16x16x32_bf16(a, b, acc[g2], 0, 0, 0);
        }
    }
    // Ms is a separate region: no barrier needed before writing it.
    {
        int col = w * 16 + m;
        float bv = b1[col];
        #pragma unroll
        for (int g2 = 0; g2 < 4; ++g2) {
            unsigned p01 = pkbf(swishf(acc[g2][0] + bv), swishf(acc[g2][1] + bv));
            unsigned p23 = pkbf(swishf(acc[g2][2] + bv), swishf(acc[g2][3] + bv));
            int base = g2 * 16 + q * 4;
            Msh[(base + 0) * 136 + col] = (unsigned short)p01;
            Msh[(base + 1) * 136 + col] = (unsigned short)(p01 >> 16);
            Msh[(base + 2) * 136 + col] = (unsigned short)p23;
            Msh[(base + 3) * 136 + col] = (unsigned short)(p23 >> 16);
        }
    }
    __syncthreads();

    floatx4 acc2[4] = {};
    #pragma unroll
    for (int c = 0; c < 4; ++c) {
        short8 b = *(const short8*)(W2p + ((size_t)(c * 8 + w) * 64 + lane) * 8);
        #pragma unroll
        for (int g2 = 0; g2 < 4; ++g2) {
            short8 a = *(const short8*)(Msh + (g2 * 16 + m) * 136 + c * 32 + q * 8);
            acc2[g2] = __builtin_amdgcn_mfma_f32_16x16x32_bf16(a, b, acc2[g2], 0, 0, 0);
        }
    }

    // ---- phase-1 epilogue: hv in registers (residual from LDS A region),
    //      fused stats, zero agg slice
    int bidx = n0 >> 12;
    int col = w * 16 + m;
    float hv[4][4];
    {
        float bv = b2[col];
        float s = 0.f, s2 = 0.f;
        #pragma unroll
        for (int g2 = 0; g2 < 4; ++g2) {
            #pragma unroll
            for (int r = 0; r < 4; ++r) {
                int row = g2 * 16 + q * 4 + r;
                float res = bf2f(SH[row * 296 + col]);   // staged normalized h
                float v = res + swishf(acc2[g2][r] + bv);
                hv[g2][r] = v;
                s += v; s2 += v * v;
            }
        }
        s  += __shfl_xor(s, 16);  s  += __shfl_xor(s, 32);
        s2 += __shfl_xor(s2, 16); s2 += __shfl_xor(s2, 32);
        if (q == 0) {
            atomicAdd(&stats[bidx * 128 + col], s);
            atomicAdd(&stats[(NB + bidx) * 128 + col], s2);
        }
    }
    {   // zero agg slice for next layer (pre-sync; agg untouched until next msg)
        int r = t & 63, cseg = t >> 6;
        float4 z = make_float4(0.f, 0.f, 0.f, 0.f);
        #pragma unroll
        for (int j = 0; j < 4; ++j)
            *(float4*)(agg + (size_t)(n0 + r) * 128 + cseg * 16 + j * 4) = z;
    }

    cg::this_grid().sync();

    // ---- phase 2: coherent stat read (device-scope atomic RMW) -> LDS
    if (t < 256) {
        int c = t & 127, which = t >> 7;
        statsS[t] = __hip_atomic_fetch_add(
            &stats[(which * NB + bidx) * 128 + c], 0.0f,
            __ATOMIC_RELAXED, __HIP_MEMORY_SCOPE_AGENT);
    }
    __syncthreads();

    {
        float mean = statsS[col] * (1.f / 4096.f);
        float sq   = statsS[128 + col] * (1.f / 4096.f);
        float inv = rsqrtf(sq - mean * mean + 1e-5f);
        #pragma unroll
        for (int g2 = 0; g2 < 4; ++g2) {
            #pragma unroll
            for (int r = 0; r < 4; ++r) {
                int row = g2 * 16 + q * 4 + r;
                float v = (hv[g2][r] - mean) * inv;
                h_bf[(size_t)(n0 + row) * 128 + col] = f2bf(v);
            }
        }
    }
}

// ---------------------------------------------------------------------------
// Conv head: 4 nodes/block, one wave per node; reads normalized h_bf.
__global__ __launch_bounds__(256) void conv_kernel(
    const unsigned short* __restrict__ h_bf, const float* __restrict__ u,
    const float* __restrict__ Wc1, const float* __restrict__ bc1,
    const float* __restrict__ Wc2, const float* __restrict__ bc2,
    float* __restrict__ out)
{
    __shared__ float hs[4][128];
    __shared__ float c1[4][8 * 40];
    int w = threadIdx.x >> 6, lane = threadIdx.x & 63;
    int n = blockIdx.x * 4 + w;
    hs[w][lane]      = bf2f(h_bf[(size_t)n * 128 + lane]);
    hs[w][lane + 64] = bf2f(h_bf[(size_t)n * 128 + lane + 64]);
    __syncthreads();
    for (int idx = lane; idx < 304; idx += 64) {
        int o = idx / 38, p = idx % 38;
        float s = bc1[o];
        #pragma unroll
        for (int k = 0; k < 16; ++k) s += hs[w][p * 3 + k] * Wc1[o * 16 + k];
        c1[w][o * 40 + p] = swishf(s);
    }
    __syncthreads();
    if (lane < TW) {
        float s = bc2[0];
        #pragma unroll
        for (int o = 0; o < 8; ++o)
            for (int k = 0; k < 14; ++k)
                s += c1[w][o * 40 + lane + k] * Wc2[o * 14 + k];
        float dt_cum = (float)(lane + 1) * (4.0f / 250.0f);
        out[n * TW + lane] = u[n * 25 + 24] + dt_cum * s;
    }
}

// ---------------------------------------------------------------------------
extern "C" void kernel_launch(void* const* d_in, const int* in_sizes, int n_in,
                              void* d_out, int out_size, void* d_ws, size_t ws_size,
                              hipStream_t stream)
{
    const float* u   = (const float*)d_in[0];
    const float* pos = (const float*)d_in[1];
    const int*   ei  = (const int*)d_in[2];
    const float* We1 = (const float*)d_in[4];
    const float* be1 = (const float*)d_in[5];
    const float* We2 = (const float*)d_in[6];
    const float* be2 = (const float*)d_in[7];
    const float* Wm1 = (const float*)d_in[8];
    const float* bm1 = (const float*)d_in[9];
    const float* Wm2 = (const float*)d_in[10];
    const float* bm2 = (const float*)d_in[11];
    const float* Wu1 = (const float*)d_in[12];
    const float* bu1 = (const float*)d_in[13];
    const float* Wu2 = (const float*)d_in[14];
    const float* bu2 = (const float*)d_in[15];
    const float* Wc1 = (const float*)d_in[16];
    const float* bc1 = (const float*)d_in[17];
    const float* Wc2 = (const float*)d_in[18];
    const float* bc2 = (const float*)d_in[19];
    float* out = (float*)d_out;

    char* base = (char*)d_ws;
    size_t off = 0;
    auto alloc = [&](size_t bytes) -> char* {
        char* r = base + off;
        off = (off + bytes + 511) & ~(size_t)511;
        return r;
    };
    unsigned short* h_bf   = (unsigned short*)alloc((size_t)N_NODES * 128 * 2);
    float*          agg    = (float*)alloc((size_t)N_NODES * 128 * 4);
    float*          posx   = (float*)alloc(N_NODES * 4);
    float*          post   = (float*)alloc(N_NODES * 4);
    float*          stats  = (float*)alloc(2 * NB * 128 * 4);
    int*            deg    = (int*)alloc(N_NODES * 4);
    int*            cursor = (int*)alloc(N_NODES * 4);
    int*            src_s  = (int*)alloc((size_t)N_EDGES * 4);
    int*            tgt_s  = (int*)alloc((size_t)N_EDGES * 4);
    unsigned short* ediff  = (unsigned short*)alloc((size_t)N_EDGES * 32 * 2);
    unsigned short* Wm1p   = (unsigned short*)alloc((size_t)6 * 9 * 4096 * 2);
    unsigned short* Wm2p   = (unsigned short*)alloc((size_t)6 * 4 * 4096 * 2);
    unsigned short* Wu1p   = (unsigned short*)alloc((size_t)6 * 9 * 4096 * 2);
    unsigned short* Wu2p   = (unsigned short*)alloc((size_t)6 * 4 * 4096 * 2);
    (void)ws_size;

    const int* srcp = ei;
    const int* tgtp = ei + N_EDGES;

    init_kernel<<<N_NODES / 256, 256, 0, stream>>>(pos, posx, post);
    hipMemsetAsync(deg, 0, N_NODES * sizeof(int), stream);
    deg_kernel<<<N_EDGES / 256, 256, 0, stream>>>(tgtp, deg);
    scan_kernel<<<1, 1024, 0, stream>>>(deg, cursor);
    scatter_kernel<<<N_EDGES / 256, 256, 0, stream>>>(srcp, tgtp, cursor, src_s, tgt_s);
    ediff_kernel<<<N_EDGES / 256, 256, 0, stream>>>(u, posx, post, src_s, tgt_s, ediff);
    encoder_kernel<<<N_NODES / 64, 256, 0, stream>>>(u, posx, post, We1, be1, We2, be2,
                                                     h_bf, agg);
    {
        int tot1 = 6 * 9 * 512;
        int tot2 = 6 * 4 * 512;
        pack_kernel<<<(tot1 + 255) / 256, 256, 0, stream>>>(Wm1, Wm1p, 283, 9, tot1);
        pack_kernel<<<(tot2 + 255) / 256, 256, 0, stream>>>(Wm2, Wm2p, 128, 4, tot2);
        pack_kernel<<<(tot1 + 255) / 256, 256, 0, stream>>>(Wu1, Wu1p, 257, 9, tot1);
        pack_kernel<<<(tot2 + 255) / 256, 256, 0, stream>>>(Wu2, Wu2p, 128, 4, tot2);
    }

    for (int l = 0; l < 6; ++l) {
        message_kernel<<<N_EDGES / 64, 512, 0, stream>>>(
            h_bf, ediff, src_s, tgt_s,
            Wm1p + (size_t)l * 9 * 4096, bm1 + l * 128,
            Wm2p + (size_t)l * 4 * 4096, bm2 + l * 128, agg, stats);
        {
            const unsigned short* W1p = Wu1p + (size_t)l * 9 * 4096;
            const float*          b1  = bu1 + l * 128;
            const unsigned short* W2p = Wu2p + (size_t)l * 4 * 4096;
            const float*          b2  = bu2 + l * 128;
            void* args[] = { (void*)&h_bf, (void*)&agg, (void*)&deg, (void*)&post,
                             (void*)&W1p, (void*)&b1, (void*)&W2p, (void*)&b2,
                             (void*)&stats };
            hipLaunchCooperativeKernel((void*)update_norm_kernel,
                                       dim3(N_NODES / 64), dim3(512),
                                       args, 0, stream);
        }
    }

    conv_kernel<<<N_NODES / 4, 256, 0, stream>>>(h_bf, u, Wc1, bc1, Wc2, bc2, out);
}

// Round 16
// 660.230 us; speedup vs baseline: 1.6960x; 1.6960x over previous
//
#include <hip/hip_runtime.h>
#include <stdint.h>

#define N_NODES 32768
#define N_EDGES 262144
#define NB 8
#define TW 25

typedef __attribute__((ext_vector_type(8))) short short8;
typedef __attribute__((ext_vector_type(4))) float floatx4;

#if defined(__has_builtin)
#if __has_builtin(__builtin_amdgcn_cvt_pk_bf16_f32)
#define HAVE_CVT_PK_BF16 1
#endif
#endif

// swish via HW approximate reciprocal (v_rcp_f32): ~1-ulp rel error,
// far below bf16 quantization; avoids the ~10-instr IEEE divide sequence.
__device__ __forceinline__ float swishf(float x) {
    return x * __builtin_amdgcn_rcpf(1.0f + __expf(-x));
}

__device__ __forceinline__ unsigned short f2bf(float x) {
    union { float f; unsigned u; } v; v.f = x;
    unsigned r = v.u + 0x7FFFu + ((v.u >> 16) & 1u);
    return (unsigned short)(r >> 16);
}
// packed f32x2 -> bf16x2 (low = a, high = b); HW v_cvt_pk_bf16_f32 on gfx950
__device__ __forceinline__ unsigned pkbf(float a, float b) {
#ifdef HAVE_CVT_PK_BF16
    typedef __attribute__((ext_vector_type(2))) __bf16 bf16x2;
    union { bf16x2 v; unsigned u; } cv;
    cv.v = __builtin_amdgcn_cvt_pk_bf16_f32(a, b);
    return cv.u;
#else
    return (unsigned)f2bf(a) | ((unsigned)f2bf(b) << 16);
#endif
}
__device__ __forceinline__ float bf2f(unsigned short b) {
    union { unsigned u; float f; } v; v.u = ((unsigned)b) << 16; return v.f;
}

// ---------------------------------------------------------------------------
__global__ void init_kernel(const float* __restrict__ pos,
                            float* __restrict__ posx, float* __restrict__ post) {
    int i = blockIdx.x * 256 + threadIdx.x;
    if (i < N_NODES) {
        post[i] = pos[i * 2 + 0] * 0.25f;
        posx[i] = pos[i * 2 + 1] * 0.0625f;
    }
}

__global__ void deg_kernel(const int* __restrict__ tgt, int* __restrict__ deg) {
    int i = blockIdx.x * 256 + threadIdx.x;
    if (i < N_EDGES) atomicAdd(&deg[tgt[i]], 1);
}

// exclusive scan of deg -> cursor, single block
__global__ __launch_bounds__(1024) void scan_kernel(const int* __restrict__ deg,
                                                    int* __restrict__ cursor) {
    __shared__ int ps[1024];
    int t = threadIdx.x;
    int base = t * 32;
    int tot = 0;
    for (int i = 0; i < 32; ++i) tot += deg[base + i];
    ps[t] = tot;
    __syncthreads();
    for (int off = 1; off < 1024; off <<= 1) {
        int v = (t >= off) ? ps[t - off] : 0;
        __syncthreads();
        ps[t] += v;
        __syncthreads();
    }
    int run = ps[t] - tot;
    for (int i = 0; i < 32; ++i) {
        cursor[base + i] = run;
        run += deg[base + i];
    }
}

// tgt-sorted edge arrays directly
__global__ void scatter_kernel(const int* __restrict__ src, const int* __restrict__ tgt,
                               int* __restrict__ cursor,
                               int* __restrict__ src_s, int* __restrict__ tgt_s) {
    int i = blockIdx.x * 256 + threadIdx.x;
    if (i < N_EDGES) {
        int tg = tgt[i];
        int p = atomicAdd(&cursor[tg], 1);
        src_s[p] = src[i];
        tgt_s[p] = tg;
    }
}

// layer-invariant edge features, tgt-sorted order: [u_diff(25), pxd, post_t, 0x5]
__global__ __launch_bounds__(256) void ediff_kernel(
    const float* __restrict__ u, const float* __restrict__ posx,
    const float* __restrict__ post,
    const int* __restrict__ src_s, const int* __restrict__ tgt_s,
    unsigned short* __restrict__ ediff)
{
    int e = blockIdx.x * 256 + threadIdx.x;
    if (e >= N_EDGES) return;
    int s = src_s[e], g = tgt_s[e];
    float fv[32];
    #pragma unroll
    for (int k = 0; k < 32; ++k) fv[k] = 0.f;
    #pragma unroll
    for (int k = 0; k < 25; ++k)
        fv[k] = u[(size_t)g * 25 + k] - u[(size_t)s * 25 + k];
    fv[25] = posx[g] - posx[s];
    fv[26] = post[g];
    unsigned pk[16];
    #pragma unroll
    for (int j = 0; j < 16; ++j) pk[j] = pkbf(fv[2 * j], fv[2 * j + 1]);
    #pragma unroll
    for (int j = 0; j < 4; ++j)
        *(uint4*)(ediff + (size_t)e * 32 + j * 8) = *(uint4*)&pk[j * 4];
}

// ---------------------------------------------------------------------------
// Pack weight into MFMA B-frag order: frag id = ((l*Kc + c)*8 + t8)*64 + lane,
// lane holds B[k=c*32+(lane>>4)*8+j][n=t8*16+(lane&15)], j=0..7.
__global__ __launch_bounds__(256) void pack_kernel(const float* __restrict__ W,
                                                   unsigned short* __restrict__ Wp,
                                                   int Kreal, int Kc, int total) {
    int id = blockIdx.x * 256 + threadIdx.x;
    if (id >= total) return;
    int lane = id & 63;
    int t8 = (id >> 6) & 7;
    int rest = id >> 9;
    int c = rest % Kc;
    int l = rest / Kc;
    int n = t8 * 16 + (lane & 15);
    int kb = c * 32 + (lane >> 4) * 8;
    short8 v;
    #pragma unroll
    for (int j = 0; j < 8; ++j) {
        int k = kb + j;
        float x = (k < Kreal) ? W[((size_t)l * Kreal + k) * 128 + n] : 0.f;
        v[j] = (short)f2bf(x);
    }
    *(short8*)(Wp + (size_t)id * 8) = v;
}

// ---------------------------------------------------------------------------
// Encoder; writes h_bf only (fp32 h eliminated); zeroes this block's agg slice
__global__ __launch_bounds__(256) void encoder_kernel(
    const float* __restrict__ u, const float* __restrict__ posx,
    const float* __restrict__ post,
    const float* __restrict__ We1, const float* __restrict__ be1,
    const float* __restrict__ We2, const float* __restrict__ be2,
    unsigned short* __restrict__ h_bf, float* __restrict__ agg)
{
    __shared__ __align__(16) float As[64 * 36];
    __shared__ __align__(16) float Ws[32 * 128];
    __shared__ __align__(16) float Ms[64 * 128];

    int t = threadIdx.x;
    int n0 = blockIdx.x * 64;
    int rg = t >> 5, cg = t & 31;

    {   // zero agg slice
        int r = t & 63, cseg = t >> 6;
        float4 z = make_float4(0.f, 0.f, 0.f, 0.f);
        #pragma unroll
        for (int j = 0; j < 8; ++j)
            *(float4*)(agg + (size_t)(n0 + r) * 128 + cseg * 32 + j * 4) = z;
    }

    float acc[8][4] = {};
    {
        int kk = t >> 3, cb = (t & 7) * 16;
        #pragma unroll
        for (int j = 0; j < 4; ++j) {
            float4 w = make_float4(0.f, 0.f, 0.f, 0.f);
            if (kk < 27) w = *(const float4*)&We1[kk * 128 + cb + j * 4];
            *(float4*)&Ws[kk * 128 + cb + j * 4] = w;
        }
        int el = t >> 2, kb = (t & 3) * 8, n = n0 + el;
        float v[8];
        #pragma unroll
        for (int j = 0; j < 8; ++j) {
            int k = kb + j;
            float x = 0.f;
            if (k < 25) x = u[n * 25 + k];
            else if (k == 25) x = posx[n];
            else if (k == 26) x = post[n];
            v[j] = x;
        }
        #pragma unroll
        for (int j = 0; j < 8; j += 4)
            *(float4*)&As[el * 36 + kb + j] = make_float4(v[j], v[j+1], v[j+2], v[j+3]);
        __syncthreads();
        #pragma unroll 4
        for (int kk2 = 0; kk2 < 32; ++kk2) {
            float4 b = *(const float4*)&Ws[kk2 * 128 + cg * 4];
            float a[8];
            #pragma unroll
            for (int i = 0; i < 8; ++i) a[i] = As[(rg * 8 + i) * 36 + kk2];
            #pragma unroll
            for (int i = 0; i < 8; ++i) {
                acc[i][0] += a[i] * b.x; acc[i][1] += a[i] * b.y;
                acc[i][2] += a[i] * b.z; acc[i][3] += a[i] * b.w;
            }
        }
        __syncthreads();
    }
    {
        float4 b1 = *(const float4*)&be1[cg * 4];
        #pragma unroll
        for (int i = 0; i < 8; ++i) {
            float4 m;
            m.x = swishf(acc[i][0] + b1.x);
            m.y = swishf(acc[i][1] + b1.y);
            m.z = swishf(acc[i][2] + b1.z);
            m.w = swishf(acc[i][3] + b1.w);
            *(float4*)&Ms[(rg * 8 + i) * 128 + cg * 4] = m;
        }
        __syncthreads();
    }
    float acc2[8][4] = {};
    for (int k0 = 0; k0 < 128; k0 += 32) {
        int kk = t >> 3, cb = (t & 7) * 16;
        #pragma unroll
        for (int j = 0; j < 4; ++j)
            *(float4*)&Ws[kk * 128 + cb + j * 4] =
                *(const float4*)&We2[(k0 + kk) * 128 + cb + j * 4];
        __syncthreads();
        #pragma unroll 4
        for (int kk2 = 0; kk2 < 32; ++kk2) {
            float4 b = *(const float4*)&Ws[kk2 * 128 + cg * 4];
            float a[8];
            #pragma unroll
            for (int i = 0; i < 8; ++i) a[i] = Ms[(rg * 8 + i) * 128 + (k0 + kk2)];
            #pragma unroll
            for (int i = 0; i < 8; ++i) {
                acc2[i][0] += a[i] * b.x; acc2[i][1] += a[i] * b.y;
                acc2[i][2] += a[i] * b.z; acc2[i][3] += a[i] * b.w;
            }
        }
        __syncthreads();
    }
    {
        float4 b2 = *(const float4*)&be2[cg * 4];
        #pragma unroll
        for (int i = 0; i < 8; ++i) {
            int n = n0 + rg * 8 + i;
            float4 o;
            o.x = swishf(acc2[i][0] + b2.x);
            o.y = swishf(acc2[i][1] + b2.y);
            o.z = swishf(acc2[i][2] + b2.z);
            o.w = swishf(acc2[i][3] + b2.w);
            uint2 pk;
            pk.x = pkbf(o.x, o.y);
            pk.y = pkbf(o.z, o.w);
            *(uint2*)(h_bf + (size_t)n * 128 + cg * 4) = pk;
        }
    }
}

// ---------------------------------------------------------------------------
// Message MLP: 64 tgt-sorted edges/block, 512 threads (8 waves), wave owns
// N-tile w over 4 M-groups. Static LDS 38 KB -> 4 blocks/CU (32 waves/CU).
__global__ __launch_bounds__(512, 8) void message_kernel(
    const unsigned short* __restrict__ h_bf,
    const unsigned short* __restrict__ ediff,
    const int* __restrict__ src_s, const int* __restrict__ tgt_s,
    const unsigned short* __restrict__ W1p, const float* __restrict__ b1,
    const unsigned short* __restrict__ W2p, const float* __restrict__ b2,
    float* __restrict__ agg, float* __restrict__ stats)
{
    __shared__ __align__(16) unsigned short SH[64 * 296];  // 37888 B
    __shared__ int tgtS[64];
    unsigned short* Msh = SH;          // 64 x 136
    unsigned short* Cs  = SH + 9216;   // byte 18432: 64 x 132

    int t = threadIdx.x;
    int e0 = blockIdx.x * 64;
    if (blockIdx.x == 0 && t < 256) {  // zero stats for this layer
        float4 z = make_float4(0.f, 0.f, 0.f, 0.f);
        *(float4*)&stats[t * 8] = z;
        *(float4*)&stats[t * 8 + 4] = z;
    }
    if (t < 64) tgtS[t] = tgt_s[e0 + t];

    // ---- stage A into LDS: 8 threads per row (r = t&63, cseg = t>>6)
    {
        int r = t & 63, cseg = t >> 6;
        int g = tgt_s[e0 + r], s = src_s[e0 + r];
        const short8* hg = (const short8*)(h_bf + (size_t)g * 128);
        const short8* hs = (const short8*)(h_bf + (size_t)s * 128);
        #pragma unroll
        for (int j = 0; j < 2; ++j) {
            int chunk = cseg * 2 + j;  // 0..15
            *(short8*)(SH + r * 296 + chunk * 8)       = hg[chunk];
            *(short8*)(SH + r * 296 + 128 + chunk * 8) = hs[chunk];
        }
        if (cseg < 4)
            *(short8*)(SH + r * 296 + 256 + cseg * 8) =
                *(const short8*)(ediff + (size_t)(e0 + r) * 32 + cseg * 8);
    }
    __syncthreads();

    int w = t >> 6, lane = t & 63, q = lane >> 4, m = lane & 15;

    // ---- GEMM1: K=288 (9 chunks), tile w, 4 M-groups
    floatx4 acc[4] = {};
    #pragma unroll
    for (int c = 0; c < 9; ++c) {
        short8 b = *(const short8*)(W1p + ((size_t)(c * 8 + w) * 64 + lane) * 8);
        #pragma unroll
        for (int g2 = 0; g2 < 4; ++g2) {
            short8 a = *(const short8*)(SH + (g2 * 16 + m) * 296 + c * 32 + q * 8);
            acc[g2] = __builtin_amdgcn_mfma_f32_16x16x32_bf16(a, b, acc[g2], 0, 0, 0);
        }
    }
    __syncthreads();  // A region dead

    // ---- epilogue 1 -> Ms (packed bf16 conversion, write b16 lo/hi)
    {
        int col = w * 16 + m;
        float bv = b1[col];
        #pragma unroll
        for (int g2 = 0; g2 < 4; ++g2) {
            unsigned p01 = pkbf(swishf(acc[g2][0] + bv), swishf(acc[g2][1] + bv));
            unsigned p23 = pkbf(swishf(acc[g2][2] + bv), swishf(acc[g2][3] + bv));
            int base = g2 * 16 + q * 4;
            Msh[(base + 0) * 136 + col] = (unsigned short)p01;
            Msh[(base + 1) * 136 + col] = (unsigned short)(p01 >> 16);
            Msh[(base + 2) * 136 + col] = (unsigned short)p23;
            Msh[(base + 3) * 136 + col] = (unsigned short)(p23 >> 16);
        }
    }
    __syncthreads();

    // ---- GEMM2: K=128 (4 chunks)
    floatx4 acc2[4] = {};
    #pragma unroll
    for (int c = 0; c < 4; ++c) {
        short8 b = *(const short8*)(W2p + ((size_t)(c * 8 + w) * 64 + lane) * 8);
        #pragma unroll
        for (int g2 = 0; g2 < 4; ++g2) {
            short8 a = *(const short8*)(Msh + (g2 * 16 + m) * 136 + c * 32 + q * 8);
            acc2[g2] = __builtin_amdgcn_mfma_f32_16x16x32_bf16(a, b, acc2[g2], 0, 0, 0);
        }
    }
    // ---- epilogue 2 -> Cs (disjoint from Ms)
    {
        int col = w * 16 + m;
        float bv = b2[col];
        #pragma unroll
        for (int g2 = 0; g2 < 4; ++g2) {
            unsigned p01 = pkbf(swishf(acc2[g2][0] + bv), swishf(acc2[g2][1] + bv));
            unsigned p23 = pkbf(swishf(acc2[g2][2] + bv), swishf(acc2[g2][3] + bv));
            int base = g2 * 16 + q * 4;
            Cs[(base + 0) * 132 + col] = (unsigned short)p01;
            Cs[(base + 1) * 132 + col] = (unsigned short)(p01 >> 16);
            Cs[(base + 2) * 132 + col] = (unsigned short)p23;
            Cs[(base + 3) * 132 + col] = (unsigned short)(p23 >> 16);
        }
    }
    __syncthreads();

    // ---- reduction: all 512 threads; col = t&127, segment = (t>>7)*16 rows
    {
        int col = t & 127, seg = t >> 7;
        int r0 = seg * 16;
        float run = 0.f;
        int prev = tgtS[r0];
        bool atStart = true;
        #pragma unroll 4
        for (int i = 0; i < 16; ++i) {
            int tg = tgtS[r0 + i];
            if (tg != prev) {
                float* dst = &agg[(size_t)prev * 128 + col];
                if (atStart) atomicAdd(dst, run);
                else *dst = run;
                run = 0.f; prev = tg; atStart = false;
            }
            run += bf2f(Cs[(r0 + i) * 132 + col]);
        }
        atomicAdd(&agg[(size_t)prev * 128 + col], run);
    }
}

// ---------------------------------------------------------------------------
// Update MLP: A region kept live (Ms separate, LDS 55.3 KB — grid 512 caps at
// 2 blocks/CU anyway). Residual read from staged A in LDS (no global h read);
// pre-norm result written as bf16 hraw. 2 barriers.
__global__ __launch_bounds__(512, 4) void update_kernel(
    unsigned short* __restrict__ hraw, const unsigned short* __restrict__ h_bf,
    float* __restrict__ agg, const int* __restrict__ deg,
    const float* __restrict__ post,
    const unsigned short* __restrict__ W1p, const float* __restrict__ b1,
    const unsigned short* __restrict__ W2p, const float* __restrict__ b2,
    float* __restrict__ stats)
{
    __shared__ __align__(16) unsigned short SH[64 * 296 + 64 * 136];  // 55296 B
    unsigned short* Msh = SH + 64 * 296;

    int t = threadIdx.x;
    int n0 = blockIdx.x * 64;

    // ---- stage A = [h_bf | agg/deg (bf16) | post-pad]: 8 threads/row
    {
        int r = t & 63, cseg = t >> 6;
        int n = n0 + r;
        const short8* hn = (const short8*)(h_bf + (size_t)n * 128);
        #pragma unroll
        for (int j = 0; j < 2; ++j) {
            int chunk = cseg * 2 + j;
            *(short8*)(SH + r * 296 + chunk * 8) = hn[chunk];
        }
        float ic = __builtin_amdgcn_rcpf(fmaxf((float)deg[n], 1.0f));
        #pragma unroll
        for (int j = 0; j < 2; ++j) {
            int unit = cseg * 2 + j;
            const float* ap = agg + (size_t)n * 128 + unit * 8;
            float4 v0 = *(const float4*)ap;
            float4 v1 = *(const float4*)(ap + 4);
            unsigned pa[4];
            pa[0] = pkbf(v0.x * ic, v0.y * ic);
            pa[1] = pkbf(v0.z * ic, v0.w * ic);
            pa[2] = pkbf(v1.x * ic, v1.y * ic);
            pa[3] = pkbf(v1.z * ic, v1.w * ic);
            *(uint4*)(SH + r * 296 + 128 + unit * 8) = *(uint4*)pa;
        }
        if (cseg < 4) {
            short8 z;
            #pragma unroll
            for (int k = 0; k < 8; ++k) z[k] = 0;
            if (cseg == 0) z[0] = (short)f2bf(post[n]);  // k=256
            *(short8*)(SH + r * 296 + 256 + cseg * 8) = z;
        }
    }
    __syncthreads();

    int w = t >> 6, lane = t & 63, q = lane >> 4, m = lane & 15;

    floatx4 acc[4] = {};
    #pragma unroll
    for (int c = 0; c < 9; ++c) {
        short8 b = *(const short8*)(W1p + ((size_t)(c * 8 + w) * 64 + lane) * 8);
        #pragma unroll
        for (int g2 = 0; g2 < 4; ++g2) {
            short8 a = *(const short8*)(SH + (g2 * 16 + m) * 296 + c * 32 + q * 8);
            acc[g2] = __builtin_amdgcn_mfma_f32_16x16x32_bf16(a, b, acc[g2], 0, 0, 0);
        }
    }
    // Ms is a separate region: no barrier needed before writing it.
    {
        int col = w * 16 + m;
        float bv = b1[col];
        #pragma unroll
        for (int g2 = 0; g2 < 4; ++g2) {
            unsigned p01 = pkbf(swishf(acc[g2][0] + bv), swishf(acc[g2][1] + bv));
            unsigned p23 = pkbf(swishf(acc[g2][2] + bv), swishf(acc[g2][3] + bv));
            int base = g2 * 16 + q * 4;
            Msh[(base + 0) * 136 + col] = (unsigned short)p01;
            Msh[(base + 1) * 136 + col] = (unsigned short)(p01 >> 16);
            Msh[(base + 2) * 136 + col] = (unsigned short)p23;
            Msh[(base + 3) * 136 + col] = (unsigned short)(p23 >> 16);
        }
    }
    __syncthreads();

    floatx4 acc2[4] = {};
    #pragma unroll
    for (int c = 0; c < 4; ++c) {
        short8 b = *(const short8*)(W2p + ((size_t)(c * 8 + w) * 64 + lane) * 8);
        #pragma unroll
        for (int g2 = 0; g2 < 4; ++g2) {
            short8 a = *(const short8*)(Msh + (g2 * 16 + m) * 136 + c * 32 + q * 8);
            acc2[g2] = __builtin_amdgcn_mfma_f32_16x16x32_bf16(a, b, acc2[g2], 0, 0, 0);
        }
    }

    // ---- epilogue: residual from LDS A region, fused stats, hraw bf16 write,
    //      zero agg slice
    int bidx = n0 >> 12;
    int col = w * 16 + m;
    float bv = b2[col];
    float s = 0.f, s2 = 0.f;
    #pragma unroll
    for (int g2 = 0; g2 < 4; ++g2) {
        #pragma unroll
        for (int r = 0; r < 4; ++r) {
            int row = g2 * 16 + q * 4 + r;
            float res = bf2f(SH[row * 296 + col]);   // staged normalized h
            float hv = res + swishf(acc2[g2][r] + bv);
            hraw[(size_t)(n0 + row) * 128 + col] = f2bf(hv);
            s += hv; s2 += hv * hv;
        }
    }
    s  += __shfl_xor(s, 16);  s  += __shfl_xor(s, 32);
    s2 += __shfl_xor(s2, 16); s2 += __shfl_xor(s2, 32);
    if (q == 0) {
        atomicAdd(&stats[bidx * 128 + col], s);
        atomicAdd(&stats[(NB + bidx) * 128 + col], s2);
    }
    {   // zero agg slice for next layer
        int r = t & 63, cseg = t >> 6;
        float4 z = make_float4(0.f, 0.f, 0.f, 0.f);
        #pragma unroll
        for (int j = 0; j < 4; ++j)
            *(float4*)(agg + (size_t)(n0 + r) * 128 + cseg * 16 + j * 4) = z;
    }
}

// ---------------------------------------------------------------------------
// Norm: hraw (bf16, pre-norm) -> h_bf (bf16, normalized). 4 channels/thread.
__global__ __launch_bounds__(256) void norm_kernel(
    const unsigned short* __restrict__ hraw,
    unsigned short* __restrict__ h_bf,
    const float* __restrict__ stats)
{
    size_t id = (size_t)blockIdx.x * 256 + threadIdx.x;  // over N*32
    int n = (int)(id >> 5), c4 = (int)(id & 31) * 4;
    int b = n >> 12;
    float4 mn = *(const float4*)&stats[b * 128 + c4];
    float4 sq = *(const float4*)&stats[(NB + b) * 128 + c4];
    uint2 rawp = *(const uint2*)(hraw + (size_t)n * 128 + c4);
    float v0 = bf2f((unsigned short)(rawp.x & 0xffffu));
    float v1 = bf2f((unsigned short)(rawp.x >> 16));
    float v2 = bf2f((unsigned short)(rawp.y & 0xffffu));
    float v3 = bf2f((unsigned short)(rawp.y >> 16));
    float m0 = mn.x * (1.f / 4096.f), m1 = mn.y * (1.f / 4096.f);
    float m2 = mn.z * (1.f / 4096.f), m3 = mn.w * (1.f / 4096.f);
    float r0 = (v0 - m0) * rsqrtf(sq.x * (1.f / 4096.f) - m0 * m0 + 1e-5f);
    float r1 = (v1 - m1) * rsqrtf(sq.y * (1.f / 4096.f) - m1 * m1 + 1e-5f);
    float r2 = (v2 - m2) * rsqrtf(sq.z * (1.f / 4096.f) - m2 * m2 + 1e-5f);
    float r3 = (v3 - m3) * rsqrtf(sq.w * (1.f / 4096.f) - m3 * m3 + 1e-5f);
    uint2 pk;
    pk.x = pkbf(r0, r1);
    pk.y = pkbf(r2, r3);
    *(uint2*)(h_bf + (size_t)n * 128 + c4) = pk;
}

// ---------------------------------------------------------------------------
// Conv head: 4 nodes/block, one wave per node; reads normalized h_bf.
__global__ __launch_bounds__(256) void conv_kernel(
    const unsigned short* __restrict__ h_bf, const float* __restrict__ u,
    const float* __restrict__ Wc1, const float* __restrict__ bc1,
    const float* __restrict__ Wc2, const float* __restrict__ bc2,
    float* __restrict__ out)
{
    __shared__ float hs[4][128];
    __shared__ float c1[4][8 * 40];
    int w = threadIdx.x >> 6, lane = threadIdx.x & 63;
    int n = blockIdx.x * 4 + w;
    hs[w][lane]      = bf2f(h_bf[(size_t)n * 128 + lane]);
    hs[w][lane + 64] = bf2f(h_bf[(size_t)n * 128 + lane + 64]);
    __syncthreads();
    for (int idx = lane; idx < 304; idx += 64) {
        int o = idx / 38, p = idx % 38;
        float s = bc1[o];
        #pragma unroll
        for (int k = 0; k < 16; ++k) s += hs[w][p * 3 + k] * Wc1[o * 16 + k];
        c1[w][o * 40 + p] = swishf(s);
    }
    __syncthreads();
    if (lane < TW) {
        float s = bc2[0];
        #pragma unroll
        for (int o = 0; o < 8; ++o)
            for (int k = 0; k < 14; ++k)
                s += c1[w][o * 40 + lane + k] * Wc2[o * 14 + k];
        float dt_cum = (float)(lane + 1) * (4.0f / 250.0f);
        out[n * TW + lane] = u[n * 25 + 24] + dt_cum * s;
    }
}

// ---------------------------------------------------------------------------
extern "C" void kernel_launch(void* const* d_in, const int* in_sizes, int n_in,
                              void* d_out, int out_size, void* d_ws, size_t ws_size,
                              hipStream_t stream)
{
    const float* u   = (const float*)d_in[0];
    const float* pos = (const float*)d_in[1];
    const int*   ei  = (const int*)d_in[2];
    const float* We1 = (const float*)d_in[4];
    const float* be1 = (const float*)d_in[5];
    const float* We2 = (const float*)d_in[6];
    const float* be2 = (const float*)d_in[7];
    const float* Wm1 = (const float*)d_in[8];
    const float* bm1 = (const float*)d_in[9];
    const float* Wm2 = (const float*)d_in[10];
    const float* bm2 = (const float*)d_in[11];
    const float* Wu1 = (const float*)d_in[12];
    const float* bu1 = (const float*)d_in[13];
    const float* Wu2 = (const float*)d_in[14];
    const float* bu2 = (const float*)d_in[15];
    const float* Wc1 = (const float*)d_in[16];
    const float* bc1 = (const float*)d_in[17];
    const float* Wc2 = (const float*)d_in[18];
    const float* bc2 = (const float*)d_in[19];
    float* out = (float*)d_out;

    char* base = (char*)d_ws;
    size_t off = 0;
    auto alloc = [&](size_t bytes) -> char* {
        char* r = base + off;
        off = (off + bytes + 511) & ~(size_t)511;
        return r;
    };
    unsigned short* hraw   = (unsigned short*)alloc((size_t)N_NODES * 128 * 2);
    unsigned short* h_bf   = (unsigned short*)alloc((size_t)N_NODES * 128 * 2);
    float*          agg    = (float*)alloc((size_t)N_NODES * 128 * 4);
    float*          posx   = (float*)alloc(N_NODES * 4);
    float*          post   = (float*)alloc(N_NODES * 4);
    float*          stats  = (float*)alloc(2 * NB * 128 * 4);
    int*            deg    = (int*)alloc(N_NODES * 4);
    int*            cursor = (int*)alloc(N_NODES * 4);
    int*            src_s  = (int*)alloc((size_t)N_EDGES * 4);
    int*            tgt_s  = (int*)alloc((size_t)N_EDGES * 4);
    unsigned short* ediff  = (unsigned short*)alloc((size_t)N_EDGES * 32 * 2);
    unsigned short* Wm1p   = (unsigned short*)alloc((size_t)6 * 9 * 4096 * 2);
    unsigned short* Wm2p   = (unsigned short*)alloc((size_t)6 * 4 * 4096 * 2);
    unsigned short* Wu1p   = (unsigned short*)alloc((size_t)6 * 9 * 4096 * 2);
    unsigned short* Wu2p   = (unsigned short*)alloc((size_t)6 * 4 * 4096 * 2);
    (void)ws_size;

    const int* srcp = ei;
    const int* tgtp = ei + N_EDGES;

    init_kernel<<<N_NODES / 256, 256, 0, stream>>>(pos, posx, post);
    hipMemsetAsync(deg, 0, N_NODES * sizeof(int), stream);
    deg_kernel<<<N_EDGES / 256, 256, 0, stream>>>(tgtp, deg);
    scan_kernel<<<1, 1024, 0, stream>>>(deg, cursor);
    scatter_kernel<<<N_EDGES / 256, 256, 0, stream>>>(srcp, tgtp, cursor, src_s, tgt_s);
    ediff_kernel<<<N_EDGES / 256, 256, 0, stream>>>(u, posx, post, src_s, tgt_s, ediff);
    encoder_kernel<<<N_NODES / 64, 256, 0, stream>>>(u, posx, post, We1, be1, We2, be2,
                                                     h_bf, agg);
    {
        int tot1 = 6 * 9 * 512;
        int tot2 = 6 * 4 * 512;
        pack_kernel<<<(tot1 + 255) / 256, 256, 0, stream>>>(Wm1, Wm1p, 283, 9, tot1);
        pack_kernel<<<(tot2 + 255) / 256, 256, 0, stream>>>(Wm2, Wm2p, 128, 4, tot2);
        pack_kernel<<<(tot1 + 255) / 256, 256, 0, stream>>>(Wu1, Wu1p, 257, 9, tot1);
        pack_kernel<<<(tot2 + 255) / 256, 256, 0, stream>>>(Wu2, Wu2p, 128, 4, tot2);
    }

    for (int l = 0; l < 6; ++l) {
        message_kernel<<<N_EDGES / 64, 512, 0, stream>>>(
            h_bf, ediff, src_s, tgt_s,
            Wm1p + (size_t)l * 9 * 4096, bm1 + l * 128,
            Wm2p + (size_t)l * 4 * 4096, bm2 + l * 128, agg, stats);
        update_kernel<<<N_NODES / 64, 512, 0, stream>>>(
            hraw, h_bf, agg, deg, post,
            Wu1p + (size_t)l * 9 * 4096, bu1 + l * 128,
            Wu2p + (size_t)l * 4 * 4096, bu2 + l * 128, stats);
        norm_kernel<<<(N_NODES * 32) / 256, 256, 0, stream>>>(hraw, h_bf, stats);
    }

    conv_kernel<<<N_NODES / 4, 256, 0, stream>>>(h_bf, u, Wc1, bc1, Wc2, bc2, out);
}